// Round 11
// baseline (294.997 us; speedup 1.0000x reference)
//
#include <hip/hip_runtime.h>
#include <hip/hip_bf16.h>

// Problem constants
#define N_ROWS 8192
#define D_DIM  1024
#define HALF_N 4096
#define N_TILES 2080             // 64*65/2 upper-triangular 128x128 tile pairs
constexpr float INV_T = 1.0f / 0.07f;   // 14.2857143 — also the fixed softmax max M

typedef __attribute__((ext_vector_type(8))) short short8;  // 8 bf16 (4 VGPRs)
typedef __attribute__((ext_vector_type(4))) float f32x4;

__device__ __forceinline__ unsigned short f2bf(float x) {
    __hip_bfloat16 h = __float2bfloat16(x);
    return *reinterpret_cast<unsigned short*>(&h);
}

// async global->LDS, 16B/lane. LDS dest is wave-uniform base + lane*16.
__device__ __forceinline__ void async_ld16(const void* g, void* lds) {
    __builtin_amdgcn_global_load_lds(
        (const __attribute__((address_space(1))) void*)g,
        (__attribute__((address_space(3))) void*)lds,
        16, 0, 0);
}

// ---------------------------------------------------------------------------
// Kernel 1: row norms + bf16 normalized copy + row_sum & done-counter zeroing.
// One wave per row. Runs before simgemm in stream order, so the counter is
// guaranteed zero when simgemm starts (ws is re-poisoned 0xAA every launch).
__global__ __launch_bounds__(256) void norm_kernel(const float* __restrict__ feat,
                                                   unsigned short* __restrict__ fn,
                                                   float* __restrict__ row_sum,
                                                   unsigned int* __restrict__ done_cnt) {
    const int w = threadIdx.x >> 6, lane = threadIdx.x & 63;
    const int row = blockIdx.x * 4 + w;
    if (blockIdx.x == 0 && threadIdx.x == 0) *done_cnt = 0u;
    const float4* src = (const float4*)(feat + (size_t)row * D_DIM);
    float4 v[4];
    float ss = 0.f;
#pragma unroll
    for (int t = 0; t < 4; ++t) {
        v[t] = src[lane + 64 * t];
        ss += v[t].x * v[t].x + v[t].y * v[t].y + v[t].z * v[t].z + v[t].w * v[t].w;
    }
#pragma unroll
    for (int off = 32; off; off >>= 1) ss += __shfl_xor(ss, off);
    float nrm = fmaxf(sqrtf(ss), 1e-8f);
    if (lane == 0) row_sum[row] = 0.f;
    const float inv = 1.0f / nrm;
    ushort4* dst = (ushort4*)(fn + (size_t)row * D_DIM);
#pragma unroll
    for (int t = 0; t < 4; ++t) {
        ushort4 o;
        o.x = f2bf(v[t].x * inv);
        o.y = f2bf(v[t].y * inv);
        o.z = f2bf(v[t].z * inv);
        o.w = f2bf(v[t].w * inv);
        dst[lane + 64 * t] = o;
    }
}

// ---------------------------------------------------------------------------
// Kernel 2: SYMMETRIC triangular sim GEMM + fixed-max exp accumulation
// + fused loss tail (last-block-done pattern).
// GEMM body is byte-identical to round 8 (the best measured: 107 us,
// SQ_LDS_BANK_CONFLICT=0, 76 VGPR): BK=32, 16 KiB LDS, 2 barriers/kt,
// rotate-within-row swizzle. All pipelining variants regressed
// (r7 dbuf +17%, r10 2-kt window +10%, r4 forced occupancy = spills).
// Tail: after the epilogue atomics each block __threadfence()s and bumps a
// device-scope counter; the block seeing N_TILES-1 reduces the loss, reading
// row_sum/s_target with AGENT-scope atomic loads (per-XCD L2s are not
// coherent — plain loads could hit a stale local line).
__global__ __launch_bounds__(256) void simgemm_kernel(const unsigned short* __restrict__ fn,
                                                      float* __restrict__ row_sum,
                                                      float* __restrict__ s_target,
                                                      unsigned int* __restrict__ done_cnt,
                                                      float* __restrict__ out) {
    __shared__ __align__(16) unsigned short As[128 * 32];   // 8 KiB
    __shared__ __align__(16) unsigned short Bs[128 * 32];   // 8 KiB
    // triangular decode: t -> (I,J), I<=J
    const int t = blockIdx.x;
    int a = (int)((sqrtf(8.f * (float)t + 1.f) - 1.f) * 0.5f);
    while ((a + 1) * (a + 2) / 2 <= t) ++a;
    while (a * (a + 1) / 2 > t) --a;
    const int I = t - a * (a + 1) / 2;   // row-tile index (<= J)
    const int J = a;                     // col-tile index
    const int r0 = I * 128, c0 = J * 128;
    const bool isdiag = (I == J);
    const bool haspair = (J == I + 32);  // contains sim[i, i+4096] for rows in I

    const int tid = threadIdx.x;
    const int w = tid >> 6, lane = tid & 63;
    const int q = lane >> 4, c16 = lane & 15;
    const int wr = (w >> 1) * 64;  // wave's row base within tile
    const int wc = (w & 1) * 64;   // wave's col base within tile
    const int wr4 = (w >> 1) * 4;  // wave's A chunk base (16-row chunks)
    const int wc4 = (w & 1) * 4;   // wave's B chunk base
    // staging: wave w stages chunks 2w, 2w+1 (rows w*32 .. w*32+31).
    const int srow = lane >> 2;                              // row within chunk
    const int skoff = ((lane & 3) ^ ((lane >> 3) & 3)) * 8;  // swizzled unit elem offset
    // fragment read element offset within a chunk (kt-invariant):
    const int loff = c16 * 32 + (q ^ ((c16 >> 1) & 3)) * 8;

    const unsigned short* pa0 = fn + (size_t)(r0 + w * 32 + srow) * D_DIM + skoff;
    const unsigned short* pa1 = pa0 + 16 * D_DIM;
    const unsigned short* pb0 = fn + (size_t)(c0 + w * 32 + srow) * D_DIM + skoff;
    const unsigned short* pb1 = pb0 + 16 * D_DIM;

    f32x4 acc[4][4];
#pragma unroll
    for (int i = 0; i < 4; ++i)
#pragma unroll
        for (int j = 0; j < 4; ++j) acc[i][j] = (f32x4){0.f, 0.f, 0.f, 0.f};

    for (int kt = 0; kt < 32; ++kt) {
        __syncthreads();  // previous k-step's reads done before overwrite
        async_ld16(pa0, (void*)&As[(w * 2 + 0) * 512]);
        async_ld16(pa1, (void*)&As[(w * 2 + 1) * 512]);
        async_ld16(pb0, (void*)&Bs[(w * 2 + 0) * 512]);
        async_ld16(pb1, (void*)&Bs[(w * 2 + 1) * 512]);
        pa0 += 32; pa1 += 32; pb0 += 32; pb1 += 32;
        __syncthreads();  // drains vmcnt(0): staging visible

        short8 af[4], bf[4];
#pragma unroll
        for (int i = 0; i < 4; ++i)
            af[i] = *(const short8*)&As[(wr4 + i) * 512 + loff];
#pragma unroll
        for (int j = 0; j < 4; ++j)
            bf[j] = *(const short8*)&Bs[(wc4 + j) * 512 + loff];
#pragma unroll
        for (int i = 0; i < 4; ++i)
#pragma unroll
            for (int j = 0; j < 4; ++j)
                acc[i][j] = __builtin_amdgcn_mfma_f32_16x16x32_bf16(af[i], bf[j], acc[i][j], 0, 0, 0);
    }

    // epilogue: e = exp(sim - M); rows-in-I sums + (I<J) cols-in-J sums.
    float cs[4] = {0.f, 0.f, 0.f, 0.f};   // per-j column partial sums
#pragma unroll
    for (int i = 0; i < 4; ++i) {
        const int growb = r0 + wr + i * 16 + q * 4;
#pragma unroll
        for (int r = 0; r < 4; ++r) {
            const int grow = growb + r;
            float s = 0.f;
#pragma unroll
            for (int j = 0; j < 4; ++j) {
                const int gcol = c0 + wc + j * 16 + c16;
                float sim = acc[i][j][r] * INV_T;
                float e = __expf(sim - INV_T);
                if (isdiag && grow == gcol) e = 0.f;   // diagonal mask
                if (haspair && gcol == grow + HALF_N) {
                    s_target[grow] = sim;              // label similarity
                    s_target[gcol] = sim;              // symmetric counterpart
                }
                s += e;
                cs[j] += e;
            }
            // row path: reduce over the 16 col-lanes of the quad
            s += __shfl_xor(s, 1);
            s += __shfl_xor(s, 2);
            s += __shfl_xor(s, 4);
            s += __shfl_xor(s, 8);
            if (c16 == 0) atomicAdd(&row_sum[grow], s);
        }
    }
    if (!isdiag) {
        // col path: reduce each cs[j] across the 4 quads, one atomic/column
#pragma unroll
        for (int j = 0; j < 4; ++j) {
            float s = cs[j];
            s += __shfl_xor(s, 16);
            s += __shfl_xor(s, 32);
            if (q == 0) atomicAdd(&row_sum[c0 + wc + j * 16 + c16], s);
        }
    }

    // ---- fused loss tail: last block to finish reduces the loss ----
    __threadfence();               // make this block's stores/atomics visible
    __shared__ unsigned int my_ord;
    __syncthreads();               // all waves' atomics issued before the bump
    if (tid == 0) my_ord = atomicAdd(done_cnt, 1u);
    __syncthreads();
    if (my_ord == N_TILES - 1) {
        __threadfence();           // acquire: order subsequent reads
        float local = 0.f;
        for (int i = tid; i < N_ROWS; i += 256) {
            float rsv = __hip_atomic_load(&row_sum[i], __ATOMIC_RELAXED,
                                          __HIP_MEMORY_SCOPE_AGENT);
            float stv = __hip_atomic_load(&s_target[i], __ATOMIC_RELAXED,
                                          __HIP_MEMORY_SCOPE_AGENT);
            local += (INV_T + __logf(rsv)) - stv;
        }
#pragma unroll
        for (int off = 32; off; off >>= 1) local += __shfl_xor(local, off);
        __shared__ float part[4];
        if ((tid & 63) == 0) part[tid >> 6] = local;
        __syncthreads();
        if (tid == 0)
            out[0] = (part[0] + part[1] + part[2] + part[3]) * (1.0f / N_ROWS);
    }
}

// ---------------------------------------------------------------------------
extern "C" void kernel_launch(void* const* d_in, const int* in_sizes, int n_in,
                              void* d_out, int out_size, void* d_ws, size_t ws_size,
                              hipStream_t stream) {
    const float* feat = (const float*)d_in[0];
    float* out = (float*)d_out;
    char* ws = (char*)d_ws;

    unsigned short* fn = (unsigned short*)ws;                 // 8192*1024 bf16 = 16 MiB
    size_t off = (size_t)N_ROWS * D_DIM * sizeof(unsigned short);
    float* row_sum = (float*)(ws + off);   off += N_ROWS * sizeof(float);
    float* s_target = (float*)(ws + off);  off += N_ROWS * sizeof(float);
    unsigned int* done_cnt = (unsigned int*)(ws + off);

    norm_kernel<<<N_ROWS / 4, 256, 0, stream>>>(feat, fn, row_sum, done_cnt);
    simgemm_kernel<<<N_TILES, 256, 0, stream>>>(fn, row_sum, s_target, done_cnt, out);
}

// Round 12
// 152.548 us; speedup vs baseline: 1.9338x; 1.9338x over previous
//
#include <hip/hip_runtime.h>
#include <hip/hip_bf16.h>

// Problem constants
#define N_ROWS 8192
#define D_DIM  1024
#define HALF_N 4096
#define N_TILES 2080             // 64*65/2 upper-triangular 128x128 tile pairs
constexpr float INV_T = 1.0f / 0.07f;   // 14.2857143 — also the fixed softmax max M

typedef __attribute__((ext_vector_type(4))) float f32x4;
typedef unsigned long u64;

// async global->LDS, 16B/lane. LDS dest is wave-uniform base + lane*16.
__device__ __forceinline__ void async_ld16(const void* g, void* lds) {
    __builtin_amdgcn_global_load_lds(
        (const __attribute__((address_space(1))) void*)g,
        (__attribute__((address_space(3))) void*)lds,
        16, 0, 0);
}

// pack 4 floats -> 4 OCP e4m3 bytes in one dword
__device__ __forceinline__ unsigned int pk_fp8x4(float a, float b, float c, float d) {
    int v = __builtin_amdgcn_cvt_pk_fp8_f32(a, b, 0, false);   // bytes 0,1
    v = __builtin_amdgcn_cvt_pk_fp8_f32(c, d, v, true);        // bytes 2,3
    return (unsigned int)v;
}

// ---------------------------------------------------------------------------
// Kernel 1: row norms + fp8 e4m3 normalized copy + fp32-exact target
// similarity + row_sum zeroing. One wave per row; pair row (i+4096 mod 8192)
// re-read (L3-resident) so s_target carries NO fp8 quantization error.
__global__ __launch_bounds__(256) void norm_kernel(const float* __restrict__ feat,
                                                   unsigned char* __restrict__ fn8,
                                                   float* __restrict__ row_sum,
                                                   float* __restrict__ s_target) {
    const int w = threadIdx.x >> 6, lane = threadIdx.x & 63;
    const int row = blockIdx.x * 4 + w;
    const int pair = (row + HALF_N) & (N_ROWS - 1);
    const float4* src = (const float4*)(feat + (size_t)row * D_DIM);
    const float4* psrc = (const float4*)(feat + (size_t)pair * D_DIM);
    float4 v[4];
    float ss = 0.f, sp = 0.f, dp = 0.f;
#pragma unroll
    for (int t = 0; t < 4; ++t) {
        v[t] = src[lane + 64 * t];
        float4 p = psrc[lane + 64 * t];
        ss += v[t].x * v[t].x + v[t].y * v[t].y + v[t].z * v[t].z + v[t].w * v[t].w;
        sp += p.x * p.x + p.y * p.y + p.z * p.z + p.w * p.w;
        dp += v[t].x * p.x + v[t].y * p.y + v[t].z * p.z + v[t].w * p.w;
    }
#pragma unroll
    for (int off = 32; off; off >>= 1) {
        ss += __shfl_xor(ss, off);
        sp += __shfl_xor(sp, off);
        dp += __shfl_xor(dp, off);
    }
    float nrm = fmaxf(sqrtf(ss), 1e-8f);
    if (lane == 0) {
        row_sum[row] = 0.f;
        s_target[row] = dp / (nrm * fmaxf(sqrtf(sp), 1e-8f)) * INV_T;
    }
    const float inv = 1.0f / nrm;
    unsigned int* dst = (unsigned int*)(fn8 + (size_t)row * D_DIM);
#pragma unroll
    for (int t = 0; t < 4; ++t)
        dst[lane + 64 * t] = pk_fp8x4(v[t].x * inv, v[t].y * inv, v[t].z * inv, v[t].w * inv);
}

// ---------------------------------------------------------------------------
// Kernel 2: SYMMETRIC triangular sim GEMM in FP8 (e4m3) + fixed-max exp acc.
// Round-8 skeleton frozen (BK bytes = 64 B/row, chunk = 16 rows x 64 B,
// rotate-within-row swizzle, 2 barriers/window, 4 async_ld16/wave/window,
// no dbuf / no forced occupancy / no device fences — r4/r7/r10/r11 lessons).
// fp8 halves staged bytes -> 16 windows of K=64 (2x mfma_f32_16x16x32_fp8_fp8
// per fragment pair) instead of 32 windows of K=32: half the barriers, half
// the LDS read cycles, same MFMA count. Fragment = 8 bytes/lane (k=q*8+j),
// read as u64 at two hoisted k-half offsets.
__global__ __launch_bounds__(256) void simgemm_kernel(const unsigned char* __restrict__ fn8,
                                                      float* __restrict__ row_sum) {
    __shared__ __align__(16) unsigned char As[128 * 64];   // 8 KiB
    __shared__ __align__(16) unsigned char Bs[128 * 64];   // 8 KiB
    // triangular decode: t -> (I,J), I<=J
    const int t = blockIdx.x;
    int a = (int)((sqrtf(8.f * (float)t + 1.f) - 1.f) * 0.5f);
    while ((a + 1) * (a + 2) / 2 <= t) ++a;
    while (a * (a + 1) / 2 > t) --a;
    const int I = t - a * (a + 1) / 2;   // row-tile index (<= J)
    const int J = a;                     // col-tile index
    const int r0 = I * 128, c0 = J * 128;
    const bool isdiag = (I == J);

    const int tid = threadIdx.x;
    const int w = tid >> 6, lane = tid & 63;
    const int q = lane >> 4, c16 = lane & 15;
    const int wr = (w >> 1) * 64;  // wave's row base within tile
    const int wc = (w & 1) * 64;   // wave's col base within tile
    const int wr4 = (w >> 1) * 4;  // wave's A chunk base (16-row chunks)
    const int wc4 = (w & 1) * 4;   // wave's B chunk base
    // staging: wave w stages chunks 2w, 2w+1 (rows w*32 .. w*32+31).
    const int srow = lane >> 2;                               // row within chunk
    const int skoff = ((lane & 3) ^ ((srow >> 1) & 3)) * 16;  // swizzled unit byte offset
    // fragment read byte offsets within a chunk (kt-invariant), k-halves h=0,1:
    const int fsw = (c16 >> 1) & 3;
    const int lbase = c16 * 64 + (q & 1) * 8;
    const int loff0 = lbase + (((q >> 1) + 0) ^ fsw) * 16;    // k = q*8+j
    const int loff1 = lbase + (((q >> 1) + 2) ^ fsw) * 16;    // k = 32+q*8+j

    const unsigned char* pa0 = fn8 + (size_t)(r0 + w * 32 + srow) * D_DIM + skoff;
    const unsigned char* pa1 = pa0 + 16 * D_DIM;
    const unsigned char* pb0 = fn8 + (size_t)(c0 + w * 32 + srow) * D_DIM + skoff;
    const unsigned char* pb1 = pb0 + 16 * D_DIM;

    f32x4 acc[4][4];
#pragma unroll
    for (int i = 0; i < 4; ++i)
#pragma unroll
        for (int j = 0; j < 4; ++j) acc[i][j] = (f32x4){0.f, 0.f, 0.f, 0.f};

    for (int kt = 0; kt < 16; ++kt) {
        __syncthreads();  // previous window's reads done before overwrite
        async_ld16(pa0, (void*)&As[(w * 2 + 0) * 1024]);
        async_ld16(pa1, (void*)&As[(w * 2 + 1) * 1024]);
        async_ld16(pb0, (void*)&Bs[(w * 2 + 0) * 1024]);
        async_ld16(pb1, (void*)&Bs[(w * 2 + 1) * 1024]);
        pa0 += 64; pa1 += 64; pb0 += 64; pb1 += 64;
        __syncthreads();  // drains vmcnt(0): staging visible

        u64 a0[4], a1[4], b0[4], b1[4];
#pragma unroll
        for (int i = 0; i < 4; ++i) {
            a0[i] = *(const u64*)&As[(wr4 + i) * 1024 + loff0];
            a1[i] = *(const u64*)&As[(wr4 + i) * 1024 + loff1];
        }
#pragma unroll
        for (int j = 0; j < 4; ++j) {
            b0[j] = *(const u64*)&Bs[(wc4 + j) * 1024 + loff0];
            b1[j] = *(const u64*)&Bs[(wc4 + j) * 1024 + loff1];
        }
#pragma unroll
        for (int i = 0; i < 4; ++i)
#pragma unroll
            for (int j = 0; j < 4; ++j) {
                acc[i][j] = __builtin_amdgcn_mfma_f32_16x16x32_fp8_fp8(
                    (long)a0[i], (long)b0[j], acc[i][j], 0, 0, 0);
                acc[i][j] = __builtin_amdgcn_mfma_f32_16x16x32_fp8_fp8(
                    (long)a1[i], (long)b1[j], acc[i][j], 0, 0, 0);
            }
    }

    // epilogue: e = exp(sim - M); rows-in-I sums + (I<J) cols-in-J sums.
    float cs[4] = {0.f, 0.f, 0.f, 0.f};   // per-j column partial sums
#pragma unroll
    for (int i = 0; i < 4; ++i) {
        const int growb = r0 + wr + i * 16 + q * 4;
#pragma unroll
        for (int r = 0; r < 4; ++r) {
            const int grow = growb + r;
            float s = 0.f;
#pragma unroll
            for (int j = 0; j < 4; ++j) {
                const int gcol = c0 + wc + j * 16 + c16;
                float sim = acc[i][j][r] * INV_T;
                float e = __expf(sim - INV_T);
                if (isdiag && grow == gcol) e = 0.f;   // diagonal mask
                s += e;
                cs[j] += e;
            }
            // row path: reduce over the 16 col-lanes of the quad
            s += __shfl_xor(s, 1);
            s += __shfl_xor(s, 2);
            s += __shfl_xor(s, 4);
            s += __shfl_xor(s, 8);
            if (c16 == 0) atomicAdd(&row_sum[grow], s);
        }
    }
    if (!isdiag) {
        // col path: reduce each cs[j] across the 4 quads, one atomic/column
#pragma unroll
        for (int j = 0; j < 4; ++j) {
            float s = cs[j];
            s += __shfl_xor(s, 16);
            s += __shfl_xor(s, 32);
            if (q == 0) atomicAdd(&row_sum[c0 + wc + j * 16 + c16], s);
        }
    }
}

// ---------------------------------------------------------------------------
// Kernel 3: loss = mean_i [ M + log(row_sum_i) - s_target_i ]
__global__ __launch_bounds__(256) void loss_kernel(const float* __restrict__ row_sum,
                                                   const float* __restrict__ s_target,
                                                   float* __restrict__ out) {
    float local = 0.f;
    for (int i = threadIdx.x; i < N_ROWS; i += 256)
        local += (INV_T + __logf(row_sum[i])) - s_target[i];
#pragma unroll
    for (int off = 32; off; off >>= 1) local += __shfl_xor(local, off);
    __shared__ float part[4];
    if ((threadIdx.x & 63) == 0) part[threadIdx.x >> 6] = local;
    __syncthreads();
    if (threadIdx.x == 0)
        out[0] = (part[0] + part[1] + part[2] + part[3]) * (1.0f / N_ROWS);
}

// ---------------------------------------------------------------------------
extern "C" void kernel_launch(void* const* d_in, const int* in_sizes, int n_in,
                              void* d_out, int out_size, void* d_ws, size_t ws_size,
                              hipStream_t stream) {
    const float* feat = (const float*)d_in[0];
    float* out = (float*)d_out;
    char* ws = (char*)d_ws;

    unsigned char* fn8 = (unsigned char*)ws;                  // 8192*1024 fp8 = 8 MiB
    size_t off = (size_t)N_ROWS * D_DIM;
    float* row_sum = (float*)(ws + off);   off += N_ROWS * sizeof(float);
    float* s_target = (float*)(ws + off);

    norm_kernel<<<N_ROWS / 4, 256, 0, stream>>>(feat, fn8, row_sum, s_target);
    simgemm_kernel<<<N_TILES, 256, 0, stream>>>(fn8, row_sum);
    loss_kernel<<<1, 256, 0, stream>>>(row_sum, s_target, out);
}